// Round 4
// baseline (244.106 us; speedup 1.0000x reference)
//
#include <hip/hip_runtime.h>

typedef unsigned short u16;
typedef short bf16x8 __attribute__((ext_vector_type(8)));
typedef float floatx4 __attribute__((ext_vector_type(4)));

#define L_TOT 65536
#define OUT_CTX 16777216           // 2*128*65536 attention elems
#define OUT_CLS (OUT_CTX + 512)

__device__ __forceinline__ u16 f2b(float f) {           // fp32 -> bf16 RNE
  unsigned int u = __float_as_uint(f);
  u += 0x7fffu + ((u >> 16) & 1u);
  return (u16)(u >> 16);
}
__device__ __forceinline__ float blo(unsigned int u) { return __uint_as_float(u << 16); }
__device__ __forceinline__ float bhi(unsigned int u) { return __uint_as_float(u & 0xffff0000u); }

// ---- prepack: W (128x128) -> A-fragment-linear bf16 [rb][ks][lane][8]
// A layout for mfma_f32_16x16x32_bf16: A[m = lane&15][k = (lane>>4)*8 + j]
__device__ __forceinline__ float pack_val(const float* W, int eo) {
  int mt = eo >> 11;
  int rem = eo & 2047;
  int ks = rem >> 9;
  int lane = (rem >> 3) & 63;
  int j = rem & 7;
  int row = mt * 16 + (lane & 15);
  int col = ks * 32 + (lane >> 4) * 8 + j;
  return W[row * 128 + col];
}

__global__ __launch_bounds__(256) void kP(
    const float* __restrict__ Wk, const float* __restrict__ Wq,
    const float* __restrict__ Wv, const float* __restrict__ Wr,
    const float* __restrict__ CLS,
    float* __restrict__ S2, float* __restrict__ Cnum2,
    u16* __restrict__ wkv, u16* __restrict__ wqf, u16* __restrict__ wrf) {
  const int t = threadIdx.x;
  if (blockIdx.x < 32) {
    #pragma unroll
    for (int i = 0; i < 8; ++i) {
      int e = blockIdx.x * 2048 + i * 256 + t;            // 0..65535
      if (e < 32768) {                                    // rb 0..7 = Wk, 8..15 = Wv
        wkv[e] = f2b(pack_val(e < 16384 ? Wk : Wv, e & 16383));
      } else if (e < 49152) {
        int eq = e - 32768;
        wqf[eq] = f2b(pack_val(Wq, eq));
      } else {
        int er = e - 49152;
        wrf[er] = f2b(pack_val(Wr, er));
      }
    }
  } else {
    // init S / Cnum slot0 with the 4 CLS columns' contributions, slot1 = 0
    int n = t >> 7, r = t & 127;
    float s = 0.f;
    #pragma unroll
    for (int j = 0; j < 4; ++j) s += __expf(CLS[(n * 128 + r) * 4 + j]);
    S2[n * 128 + r] = s;
    S2[256 + n * 128 + r] = 0.f;
    for (int i = 0; i < 16; ++i) {
      int o = t * 16 + i;                                 // [n][h][kc][vc]
      int nn = o >> 11;
      int rem = o & 2047;
      int h = rem >> 8;
      int kc = (rem >> 4) & 15;
      int vc = rem & 15;
      float a = 0.f;
      #pragma unroll
      for (int j = 0; j < 4; ++j)
        a += __expf(CLS[(nn * 128 + h * 16 + kc) * 4 + j]) *
             CLS[(nn * 128 + h * 16 + vc) * 4 + j];
      Cnum2[o] = a;
      Cnum2[4096 + o] = 0.f;
    }
  }
}

// ---- reduce kernel v4: 1024 blocks x 2 tiles of 64 cols, 3 blocks/CU target.
//      ks-double-buffered W frags (32 VGPR), half-tile register prefetch (16 VGPR).
__global__ __launch_bounds__(256, 3) void kA(
    const float* __restrict__ x, const float* __restrict__ bk,
    const float* __restrict__ bv, float* __restrict__ S2,
    float* __restrict__ Cnum2, const u16* __restrict__ wkv) {
  __shared__ __align__(16) u16 xT[64][136];   // [col][ch]
  __shared__ __align__(16) u16 ev[256][72];   // rows 0..127 = E(bf16), 128..255 = V(bf16)
  const int t = threadIdx.x;
  const int w = t >> 6, lane = t & 63;
  const int quad = lane >> 4, lm = lane & 15;
  const int n = blockIdx.x >> 9;              // 1024 blocks
  const int l0base = (blockIdx.x & 511) << 7; // 128 cols per block
  const int slot = blockIdx.x & 1;

  const int sc = t >> 4;                      // staging: channel sub-index 0..15
  const int sl4 = t & 15;                     // float4 index along l

  // prefetch first half of tile 0 (channels 0..63)
  float4 pf[4];
  #pragma unroll
  for (int i = 0; i < 4; ++i) {
    int c = i * 16 + sc;
    pf[i] = *(const float4*)(x + (((size_t)(n * 128 + c)) << 16) + l0base + sl4 * 4);
  }

  // bias per (mt, j), loaded once. wave w owns key rows 32w..32w+31, value rows 128+32w..
  float bias_[4][4];
  #pragma unroll
  for (int mt = 0; mt < 4; ++mt)
    #pragma unroll
    for (int j = 0; j < 4; ++j) {
      int r = w * 32 + (mt & 1) * 16 + quad * 4 + j;
      bias_[mt][j] = (mt < 2) ? bk[r] : bv[r];
    }

  floatx4 z4 = {0.f, 0.f, 0.f, 0.f};
  floatx4 cacc[2] = {z4, z4};                 // context accumulators (2 heads per wave)
  float sacc = 0.f;                           // S accumulator (threads 0..127)

  for (int tile = 0; tile < 2; ++tile) {
    // store prefetched half, then JIT-load + store second half (channels 64..127)
    #pragma unroll
    for (int i = 0; i < 4; ++i) {
      int cc = i * 16 + sc;
      int col = sl4 * 4;
      xT[col + 0][cc] = f2b(pf[i].x);
      xT[col + 1][cc] = f2b(pf[i].y);
      xT[col + 2][cc] = f2b(pf[i].z);
      xT[col + 3][cc] = f2b(pf[i].w);
    }
    {
      int l0 = l0base + tile * 64;
      float4 v2[4];
      #pragma unroll
      for (int i = 0; i < 4; ++i) {
        int c = (i + 4) * 16 + sc;
        v2[i] = *(const float4*)(x + (((size_t)(n * 128 + c)) << 16) + l0 + sl4 * 4);
      }
      #pragma unroll
      for (int i = 0; i < 4; ++i) {
        int cc = (i + 4) * 16 + sc;
        int col = sl4 * 4;
        xT[col + 0][cc] = f2b(v2[i].x);
        xT[col + 1][cc] = f2b(v2[i].y);
        xT[col + 2][cc] = f2b(v2[i].z);
        xT[col + 3][cc] = f2b(v2[i].w);
      }
    }
    __syncthreads();                          // barrier A

    floatx4 acc[4][4];
    #pragma unroll
    for (int mt = 0; mt < 4; ++mt)
      #pragma unroll
      for (int nt = 0; nt < 4; ++nt) acc[mt][nt] = z4;

    // ks-outer GEMM, W frags double-buffered (rb: mt<2 -> keys 2w+mt, else values 8+2w+mt-2)
    bf16x8 wfk[2][4];
    #pragma unroll
    for (int mt = 0; mt < 4; ++mt) {
      int rb = (mt < 2) ? (2 * w + mt) : (8 + 2 * w + (mt - 2));
      wfk[0][mt] = *(const bf16x8*)(wkv + (((rb * 4 + 0) * 64 + lane) * 8));
    }
    #pragma unroll
    for (int ks = 0; ks < 4; ++ks) {
      int cur = ks & 1;
      if (ks < 3) {
        #pragma unroll
        for (int mt = 0; mt < 4; ++mt) {
          int rb = (mt < 2) ? (2 * w + mt) : (8 + 2 * w + (mt - 2));
          wfk[cur ^ 1][mt] = *(const bf16x8*)(wkv + (((rb * 4 + ks + 1) * 64 + lane) * 8));
        }
      }
      #pragma unroll
      for (int nt = 0; nt < 4; ++nt) {
        bf16x8 b = *(const bf16x8*)(&xT[nt * 16 + lm][ks * 32 + quad * 8]);
        #pragma unroll
        for (int mt = 0; mt < 4; ++mt)
          acc[mt][nt] = __builtin_amdgcn_mfma_f32_16x16x32_bf16(wfk[cur][mt], b, acc[mt][nt], 0, 0, 0);
      }
    }

    // epilogue: bias, exp on key rows; write E/V bf16 to LDS. C-layout: row=quad*4+j, col=lm
    #pragma unroll
    for (int mt = 0; mt < 4; ++mt)
      #pragma unroll
      for (int j = 0; j < 4; ++j) {
        int R = ((mt < 2) ? 0 : 128) + w * 32 + (mt & 1) * 16 + quad * 4 + j;
        #pragma unroll
        for (int nt = 0; nt < 4; ++nt) {
          float v = acc[mt][nt][j] + bias_[mt][j];
          if (mt < 2) v = __expf(v);
          ev[R][nt * 16 + lm] = f2b(v);
        }
      }

    // prefetch first half of next tile (overlaps barrier + ctx/S phase)
    if (tile < 1) {
      int l0 = l0base + 64;
      #pragma unroll
      for (int i = 0; i < 4; ++i) {
        int c = i * 16 + sc;
        pf[i] = *(const float4*)(x + (((size_t)(n * 128 + c)) << 16) + l0 + sl4 * 4);
      }
    }
    __syncthreads();                          // barrier B

    // context: D[kc][vc] += sum_l E[h*16+kc,l] * V[h*16+vc,l]  (accumulate in regs)
    #pragma unroll
    for (int hh = 0; hh < 2; ++hh) {
      int h = w * 2 + hh;
      #pragma unroll
      for (int ks = 0; ks < 2; ++ks) {
        bf16x8 aE = *(const bf16x8*)(&ev[h * 16 + lm][ks * 32 + quad * 8]);
        bf16x8 bV = *(const bf16x8*)(&ev[128 + h * 16 + lm][ks * 32 + quad * 8]);
        cacc[hh] = __builtin_amdgcn_mfma_f32_16x16x32_bf16(aE, bV, cacc[hh], 0, 0, 0);
      }
    }
    // S partials: row sums of E (accumulate in regs)
    if (t < 128) {
      #pragma unroll
      for (int i = 0; i < 8; ++i) {
        uint4 u = *(const uint4*)(&ev[t][i * 8]);
        sacc += blo(u.x) + bhi(u.x) + blo(u.y) + bhi(u.y) +
                blo(u.z) + bhi(u.z) + blo(u.w) + bhi(u.w);
      }
    }
    // next iteration's barrier A protects ev rewrites against these reads
  }

  // one atomic set per block, 2-slot to halve same-address contention
  float* Cn = Cnum2 + slot * 4096;
  #pragma unroll
  for (int hh = 0; hh < 2; ++hh) {
    int h = w * 2 + hh;
    #pragma unroll
    for (int j = 0; j < 4; ++j)
      atomicAdd(&Cn[((n * 8 + h) * 16 + quad * 4 + j) * 16 + lm], cacc[hh][j]);
  }
  if (t < 128) atomicAdd(&S2[slot * 256 + n * 128 + t], sacc);
}

// ---- map kernel v4: 1024 blocks x 2 tiles, fused ctx-finalize (kF folded in).
__global__ __launch_bounds__(256, 3) void kB(
    const float* __restrict__ x, const float* __restrict__ bq,
    const float* __restrict__ br, const u16* __restrict__ wqf,
    const u16* __restrict__ wrf, const float* __restrict__ S2,
    const float* __restrict__ Cnum2, const float* __restrict__ CLS,
    float* __restrict__ out) {
  __shared__ __align__(16) u16 xT[64][136];
  __shared__ __align__(16) u16 qT[64][136];    // softmaxed queries, [col][ch] bf16
  __shared__ __align__(16) u16 aT[64][136];    // att, [col][ch] bf16
  const int t = threadIdx.x;
  const int w = t >> 6, lane = t & 63;
  const int quad = lane >> 4, lm = lane & 15;
  const int n = blockIdx.x >> 9;
  const int l0base = (blockIdx.x & 511) << 7;

  const int sc = t >> 4;
  const int sl4 = t & 15;

  float4 pf[4];
  #pragma unroll
  for (int i = 0; i < 4; ++i) {
    int c = i * 16 + sc;
    pf[i] = *(const float4*)(x + (((size_t)(n * 128 + c)) << 16) + l0base + sl4 * 4);
  }

  // fused kF: build this wave's ctx A-frags from 2-slot Cnum/S (zero-padded k>=16)
  bf16x8 aC[2];
  #pragma unroll
  for (int mt = 0; mt < 2; ++mt) {
    int h = w * 2 + mt;
    short frag[8];
    #pragma unroll
    for (int j = 0; j < 8; ++j) {
      int k = quad * 8 + j;                    // 0..31 over quad
      float v = 0.f;
      if (k < 16) {
        int ci = ((n * 8 + h) * 16 + k) * 16 + lm;
        float c = Cnum2[ci] + Cnum2[4096 + ci];
        float s = S2[n * 128 + h * 16 + k] + S2[256 + n * 128 + h * 16 + k];
        v = c / s;
      }
      frag[j] = (short)f2b(v);
    }
    aC[mt] = *(bf16x8*)frag;
  }

  // block 0: emit context_last + CLS_out (head 7)
  if (blockIdx.x == 0) {
    for (int e = t; e < 512; e += 256) {
      int nn = e >> 8;
      int kc = (e >> 4) & 15;
      int vc = e & 15;
      int ci = ((nn * 8 + 7) * 16 + kc) * 16 + vc;
      float c = Cnum2[ci] + Cnum2[4096 + ci];
      float s = S2[nn * 128 + 112 + kc] + S2[256 + nn * 128 + 112 + kc];
      out[OUT_CTX + e] = c / s;
    }
    if (t < 128) {
      int nn = t >> 6;
      int vc = (t >> 2) & 15;
      int j = t & 3;
      float den = 0.f, num = 0.f;
      #pragma unroll
      for (int kc = 0; kc < 16; ++kc) {
        float e_ = __expf(CLS[(nn * 128 + 112 + kc) * 4 + j]);
        int ci = ((nn * 8 + 7) * 16 + kc) * 16 + vc;
        float c = Cnum2[ci] + Cnum2[4096 + ci];
        float s = S2[nn * 128 + 112 + kc] + S2[256 + nn * 128 + 112 + kc];
        den += e_;
        num += e_ * (c / s);
      }
      out[OUT_CLS + t] = num / den;
    }
  }

  float bqv_[2][4], brv[2][4];
  #pragma unroll
  for (int mt = 0; mt < 2; ++mt)
    #pragma unroll
    for (int j = 0; j < 4; ++j) {
      bqv_[mt][j] = bq[(w * 2 + mt) * 16 + quad * 4 + j];
      brv[mt][j] = br[(w * 2 + mt) * 16 + quad * 4 + j];
    }

  floatx4 z4 = {0.f, 0.f, 0.f, 0.f};

  for (int tile = 0; tile < 2; ++tile) {
    int l0 = l0base + tile * 64;
    #pragma unroll
    for (int i = 0; i < 4; ++i) {
      int cc = i * 16 + sc;
      int col = sl4 * 4;
      xT[col + 0][cc] = f2b(pf[i].x);
      xT[col + 1][cc] = f2b(pf[i].y);
      xT[col + 2][cc] = f2b(pf[i].z);
      xT[col + 3][cc] = f2b(pf[i].w);
    }
    {
      float4 v2[4];
      #pragma unroll
      for (int i = 0; i < 4; ++i) {
        int c = (i + 4) * 16 + sc;
        v2[i] = *(const float4*)(x + (((size_t)(n * 128 + c)) << 16) + l0 + sl4 * 4);
      }
      #pragma unroll
      for (int i = 0; i < 4; ++i) {
        int cc = (i + 4) * 16 + sc;
        int col = sl4 * 4;
        xT[col + 0][cc] = f2b(v2[i].x);
        xT[col + 1][cc] = f2b(v2[i].y);
        xT[col + 2][cc] = f2b(v2[i].z);
        xT[col + 3][cc] = f2b(v2[i].w);
      }
    }
    __syncthreads();                          // barrier A

    floatx4 acc[2][4];
    #pragma unroll
    for (int mt = 0; mt < 2; ++mt)
      #pragma unroll
      for (int nt = 0; nt < 4; ++nt) acc[mt][nt] = z4;

    // ks-outer queries GEMM, wq double-buffered
    bf16x8 wqk[2][2];
    #pragma unroll
    for (int mt = 0; mt < 2; ++mt)
      wqk[0][mt] = *(const bf16x8*)(wqf + ((((w * 2 + mt) * 4 + 0) * 64 + lane) * 8));
    #pragma unroll
    for (int ks = 0; ks < 4; ++ks) {
      int cur = ks & 1;
      if (ks < 3) {
        #pragma unroll
        for (int mt = 0; mt < 2; ++mt)
          wqk[cur ^ 1][mt] = *(const bf16x8*)(wqf + ((((w * 2 + mt) * 4 + ks + 1) * 64 + lane) * 8));
      }
      #pragma unroll
      for (int nt = 0; nt < 4; ++nt) {
        bf16x8 b = *(const bf16x8*)(&xT[nt * 16 + lm][ks * 32 + quad * 8]);
        #pragma unroll
        for (int mt = 0; mt < 2; ++mt)
          acc[mt][nt] = __builtin_amdgcn_mfma_f32_16x16x32_bf16(wqk[cur][mt], b, acc[mt][nt], 0, 0, 0);
      }
    }

    // per-column softmax over the 16 channels of each head (wave-local)
    #pragma unroll
    for (int mt = 0; mt < 2; ++mt) {
      int h = w * 2 + mt;
      #pragma unroll
      for (int nt = 0; nt < 4; ++nt) {
        float e[4];
        float ssum = 0.f;
        #pragma unroll
        for (int j = 0; j < 4; ++j) {
          e[j] = __expf(acc[mt][nt][j] + bqv_[mt][j]);
          ssum += e[j];
        }
        ssum += __shfl_xor(ssum, 16);
        ssum += __shfl_xor(ssum, 32);
        float inv = 1.f / ssum;
        #pragma unroll
        for (int j = 0; j < 4; ++j)
          qT[nt * 16 + lm][h * 16 + quad * 4 + j] = f2b(e[j] * inv);
      }
    }
    // same wave wrote these qT rows -> no barrier before reading them back (DS in-order)

    // att[h*16+vc, col] = sum_kc ctx[h,kc,vc] * q[h*16+kc, col]
    #pragma unroll
    for (int mt = 0; mt < 2; ++mt) {
      int h = w * 2 + mt;
      #pragma unroll
      for (int nt = 0; nt < 4; ++nt) {
        bf16x8 bq_ = *(const bf16x8*)(&qT[nt * 16 + lm][h * 16 + (quad & 1) * 8]);
        floatx4 d = __builtin_amdgcn_mfma_f32_16x16x32_bf16(aC[mt], bq_, z4, 0, 0, 0);
        #pragma unroll
        for (int j = 0; j < 4; ++j)
          aT[nt * 16 + lm][h * 16 + quad * 4 + j] = f2b(d[j]);
      }
    }

    // prefetch first half of next tile
    if (tile < 1) {
      int l0n = l0base + 64;
      #pragma unroll
      for (int i = 0; i < 4; ++i) {
        int c = i * 16 + sc;
        pf[i] = *(const float4*)(x + (((size_t)(n * 128 + c)) << 16) + l0n + sl4 * 4);
      }
    }
    __syncthreads();                          // barrier B (all heads' att rows ready)

    floatx4 acc2[2][4];
    #pragma unroll
    for (int mt = 0; mt < 2; ++mt)
      #pragma unroll
      for (int nt = 0; nt < 4; ++nt) acc2[mt][nt] = z4;

    bf16x8 wrk[2][2];
    #pragma unroll
    for (int mt = 0; mt < 2; ++mt)
      wrk[0][mt] = *(const bf16x8*)(wrf + ((((w * 2 + mt) * 4 + 0) * 64 + lane) * 8));
    #pragma unroll
    for (int ks = 0; ks < 4; ++ks) {
      int cur = ks & 1;
      if (ks < 3) {
        #pragma unroll
        for (int mt = 0; mt < 2; ++mt)
          wrk[cur ^ 1][mt] = *(const bf16x8*)(wrf + ((((w * 2 + mt) * 4 + ks + 1) * 64 + lane) * 8));
      }
      #pragma unroll
      for (int nt = 0; nt < 4; ++nt) {
        bf16x8 b = *(const bf16x8*)(&aT[nt * 16 + lm][ks * 32 + quad * 8]);
        #pragma unroll
        for (int mt = 0; mt < 2; ++mt)
          acc2[mt][nt] = __builtin_amdgcn_mfma_f32_16x16x32_bf16(wrk[cur][mt], b, acc2[mt][nt], 0, 0, 0);
      }
    }

    #pragma unroll
    for (int mt = 0; mt < 2; ++mt)
      #pragma unroll
      for (int j = 0; j < 4; ++j) {
        int R = (w * 2 + mt) * 16 + quad * 4 + j;
        #pragma unroll
        for (int nt = 0; nt < 4; ++nt)
          out[(((size_t)(n * 128 + R)) << 16) + l0 + nt * 16 + lm] = acc2[mt][nt][j] + brv[mt][j];
      }
    // next iteration's barrier A protects xT/aT rewrites against this tile's reads
  }
}

extern "C" void kernel_launch(void* const* d_in, const int* in_sizes, int n_in,
                              void* d_out, int out_size, void* d_ws, size_t ws_size,
                              hipStream_t stream) {
  const float* x   = (const float*)d_in[0];
  const float* CLS = (const float*)d_in[1];
  const float* Wk  = (const float*)d_in[2];
  const float* bk  = (const float*)d_in[3];
  const float* Wq  = (const float*)d_in[4];
  const float* bq  = (const float*)d_in[5];
  const float* Wv  = (const float*)d_in[6];
  const float* bv  = (const float*)d_in[7];
  const float* Wr  = (const float*)d_in[8];
  const float* br  = (const float*)d_in[9];
  float* out = (float*)d_out;
  char* ws = (char*)d_ws;
  float* S2    = (float*)(ws + 0);        // 2 slots x 2n x 128 f32 = 2048 B
  float* Cnum2 = (float*)(ws + 2048);     // 2 slots x 4096 f32 = 32768 B
  u16* wkv     = (u16*)(ws + 34816);      // 16*4*64*8 bf16 = 65536 B
  u16* wqf     = (u16*)(ws + 100352);     // 8*4*64*8 bf16 = 32768 B
  u16* wrf     = (u16*)(ws + 133120);     // 8*4*64*8 bf16 = 32768 B

  kP<<<33, 256, 0, stream>>>(Wk, Wq, Wv, Wr, CLS, S2, Cnum2, wkv, wqf, wrf);
  kA<<<1024, 256, 0, stream>>>(x, bk, bv, S2, Cnum2, wkv);
  kB<<<1024, 256, 0, stream>>>(x, bq, br, wqf, wrf, S2, Cnum2, CLS, out);
}

// Round 5
// 167.930 us; speedup vs baseline: 1.4536x; 1.4536x over previous
//
#include <hip/hip_runtime.h>

typedef unsigned short u16;
typedef short bf16x8 __attribute__((ext_vector_type(8)));
typedef float floatx4 __attribute__((ext_vector_type(4)));

#define L_TOT 65536
#define OUT_CTX 16777216           // 2*128*65536 attention elems
#define OUT_CLS (OUT_CTX + 512)

__device__ __forceinline__ u16 f2b(float f) {           // fp32 -> bf16 RNE
  unsigned int u = __float_as_uint(f);
  u += 0x7fffu + ((u >> 16) & 1u);
  return (u16)(u >> 16);
}
__device__ __forceinline__ float blo(unsigned int u) { return __uint_as_float(u << 16); }
__device__ __forceinline__ float bhi(unsigned int u) { return __uint_as_float(u & 0xffff0000u); }

// ---- prepack: W (128x128) -> A-fragment-linear bf16 [rb][ks][lane][8]
// A layout for mfma_f32_16x16x32_bf16: A[m = lane&15][k = (lane>>4)*8 + j]
__device__ __forceinline__ float pack_val(const float* W, int eo) {
  int mt = eo >> 11;
  int rem = eo & 2047;
  int ks = rem >> 9;
  int lane = (rem >> 3) & 63;
  int j = rem & 7;
  int row = mt * 16 + (lane & 15);
  int col = ks * 32 + (lane >> 4) * 8 + j;
  return W[row * 128 + col];
}

__global__ __launch_bounds__(256) void kP(
    const float* __restrict__ Wk, const float* __restrict__ Wq,
    const float* __restrict__ Wv, const float* __restrict__ Wr,
    const float* __restrict__ CLS,
    float* __restrict__ S2, float* __restrict__ Cnum2,
    u16* __restrict__ wkv, u16* __restrict__ wqf, u16* __restrict__ wrf) {
  const int t = threadIdx.x;
  if (blockIdx.x < 32) {
    #pragma unroll
    for (int i = 0; i < 8; ++i) {
      int e = blockIdx.x * 2048 + i * 256 + t;            // 0..65535
      if (e < 32768) {                                    // rb 0..7 = Wk, 8..15 = Wv
        wkv[e] = f2b(pack_val(e < 16384 ? Wk : Wv, e & 16383));
      } else if (e < 49152) {
        int eq = e - 32768;
        wqf[eq] = f2b(pack_val(Wq, eq));
      } else {
        int er = e - 49152;
        wrf[er] = f2b(pack_val(Wr, er));
      }
    }
  } else {
    // init S / Cnum slot0 with the 4 CLS columns' contributions, slot1 = 0
    int n = t >> 7, r = t & 127;
    float s = 0.f;
    #pragma unroll
    for (int j = 0; j < 4; ++j) s += __expf(CLS[(n * 128 + r) * 4 + j]);
    S2[n * 128 + r] = s;
    S2[256 + n * 128 + r] = 0.f;
    for (int i = 0; i < 16; ++i) {
      int o = t * 16 + i;                                 // [n][h][kc][vc]
      int nn = o >> 11;
      int rem = o & 2047;
      int h = rem >> 8;
      int kc = (rem >> 4) & 15;
      int vc = rem & 15;
      float a = 0.f;
      #pragma unroll
      for (int j = 0; j < 4; ++j)
        a += __expf(CLS[(nn * 128 + h * 16 + kc) * 4 + j]) *
             CLS[(nn * 128 + h * 16 + vc) * 4 + j];
      Cnum2[o] = a;
      Cnum2[4096 + o] = 0.f;
    }
  }
}

// ---- reduce kernel (R3 structure): 512 blocks x 4 tiles of 64 cols. W frags + bias
//      loaded once into regs, context/S in regs across tiles, full-tile register
//      prefetch, one 2-slot atomic set per block. NO min-waves bound (spills!).
__global__ __launch_bounds__(256) void kA(
    const float* __restrict__ x, const float* __restrict__ bk,
    const float* __restrict__ bv, float* __restrict__ S2,
    float* __restrict__ Cnum2, const u16* __restrict__ wkv) {
  __shared__ __align__(16) u16 xT[64][136];   // [col][ch]
  __shared__ __align__(16) u16 ev[256][72];   // rows 0..127 = E(bf16), 128..255 = V(bf16)
  const int t = threadIdx.x;
  const int w = t >> 6, lane = t & 63;
  const int quad = lane >> 4, lm = lane & 15;
  const int n = blockIdx.x >> 8;              // 512 blocks
  const int l0base = (blockIdx.x & 255) << 8; // 256 cols per block
  const int slot = blockIdx.x & 1;

  const int sc = t >> 4;                      // staging: channel sub-index 0..15
  const int sl4 = t & 15;                     // float4 index along l

  // prefetch tile 0 (issue before the L2-bound wf loads: HBM latency is longer)
  float4 pf[8];
  #pragma unroll
  for (int i = 0; i < 8; ++i) {
    int c = i * 16 + sc;
    pf[i] = *(const float4*)(x + (((size_t)(n * 128 + c)) << 16) + l0base + sl4 * 4);
  }

  // W fragments: wave w owns key row-blocks {2w,2w+1} and value row-blocks {8+2w,8+2w+1}
  bf16x8 wf[4][4];
  #pragma unroll
  for (int mt = 0; mt < 4; ++mt) {
    int rb = (mt < 2) ? (2 * w + mt) : (8 + 2 * w + (mt - 2));
    #pragma unroll
    for (int ks = 0; ks < 4; ++ks)
      wf[mt][ks] = *(const bf16x8*)(wkv + (((rb * 4 + ks) * 64 + lane) * 8));
  }
  // bias per (mt, j), loaded once
  float bias_[4][4];
  #pragma unroll
  for (int mt = 0; mt < 4; ++mt)
    #pragma unroll
    for (int j = 0; j < 4; ++j) {
      int r = w * 32 + (mt & 1) * 16 + quad * 4 + j;
      bias_[mt][j] = (mt < 2) ? bk[r] : bv[r];
    }

  floatx4 z4 = {0.f, 0.f, 0.f, 0.f};
  floatx4 cacc[2] = {z4, z4};                 // context accumulators (2 heads per wave)
  float sacc = 0.f;                           // S accumulator (threads 0..127)

  for (int tile = 0; tile < 4; ++tile) {
    // store prefetched x-tile (transposed bf16)
    #pragma unroll
    for (int i = 0; i < 8; ++i) {
      int cc = i * 16 + sc;
      int col = sl4 * 4;
      xT[col + 0][cc] = f2b(pf[i].x);
      xT[col + 1][cc] = f2b(pf[i].y);
      xT[col + 2][cc] = f2b(pf[i].z);
      xT[col + 3][cc] = f2b(pf[i].w);
    }
    __syncthreads();                          // barrier A

    floatx4 acc[4][4];
    #pragma unroll
    for (int mt = 0; mt < 4; ++mt)
      #pragma unroll
      for (int nt = 0; nt < 4; ++nt) acc[mt][nt] = z4;

    #pragma unroll
    for (int nt = 0; nt < 4; ++nt)
      #pragma unroll
      for (int ks = 0; ks < 4; ++ks) {
        bf16x8 b = *(const bf16x8*)(&xT[nt * 16 + lm][ks * 32 + quad * 8]);
        #pragma unroll
        for (int mt = 0; mt < 4; ++mt)
          acc[mt][nt] = __builtin_amdgcn_mfma_f32_16x16x32_bf16(wf[mt][ks], b, acc[mt][nt], 0, 0, 0);
      }

    // epilogue: bias, exp on key rows; write E/V bf16 to LDS. C-layout: row=quad*4+j, col=lm
    #pragma unroll
    for (int mt = 0; mt < 4; ++mt)
      #pragma unroll
      for (int j = 0; j < 4; ++j) {
        int R = ((mt < 2) ? 0 : 128) + w * 32 + (mt & 1) * 16 + quad * 4 + j;
        #pragma unroll
        for (int nt = 0; nt < 4; ++nt) {
          float v = acc[mt][nt][j] + bias_[mt][j];
          if (mt < 2) v = __expf(v);
          ev[R][nt * 16 + lm] = f2b(v);
        }
      }

    // prefetch next tile (overlaps barrier + ctx/S phase)
    if (tile < 3) {
      int l0 = l0base + (tile + 1) * 64;
      #pragma unroll
      for (int i = 0; i < 8; ++i) {
        int c = i * 16 + sc;
        pf[i] = *(const float4*)(x + (((size_t)(n * 128 + c)) << 16) + l0 + sl4 * 4);
      }
    }
    __syncthreads();                          // barrier B

    // context: D[kc][vc] += sum_l E[h*16+kc,l] * V[h*16+vc,l]  (accumulate in regs)
    #pragma unroll
    for (int hh = 0; hh < 2; ++hh) {
      int h = w * 2 + hh;
      #pragma unroll
      for (int ks = 0; ks < 2; ++ks) {
        bf16x8 aE = *(const bf16x8*)(&ev[h * 16 + lm][ks * 32 + quad * 8]);
        bf16x8 bV = *(const bf16x8*)(&ev[128 + h * 16 + lm][ks * 32 + quad * 8]);
        cacc[hh] = __builtin_amdgcn_mfma_f32_16x16x32_bf16(aE, bV, cacc[hh], 0, 0, 0);
      }
    }
    // S partials: row sums of E (accumulate in regs)
    if (t < 128) {
      #pragma unroll
      for (int i = 0; i < 8; ++i) {
        uint4 u = *(const uint4*)(&ev[t][i * 8]);
        sacc += blo(u.x) + bhi(u.x) + blo(u.y) + bhi(u.y) +
                blo(u.z) + bhi(u.z) + blo(u.w) + bhi(u.w);
      }
    }
    // next iteration's barrier A protects ev rewrites against these reads
  }

  // one atomic set per block, 2-slot to halve same-address contention
  float* Cn = Cnum2 + slot * 4096;
  #pragma unroll
  for (int hh = 0; hh < 2; ++hh) {
    int h = w * 2 + hh;
    #pragma unroll
    for (int j = 0; j < 4; ++j)
      atomicAdd(&Cn[((n * 8 + h) * 16 + quad * 4 + j) * 16 + lm], cacc[hh][j]);
  }
  if (t < 128) atomicAdd(&S2[slot * 256 + n * 128 + t], sacc);
}

// ---- map kernel (R3 structure + fused kF): 512 blocks x 4 tiles.
__global__ __launch_bounds__(256) void kB(
    const float* __restrict__ x, const float* __restrict__ bq,
    const float* __restrict__ br, const u16* __restrict__ wqf,
    const u16* __restrict__ wrf, const float* __restrict__ S2,
    const float* __restrict__ Cnum2, const float* __restrict__ CLS,
    float* __restrict__ out) {
  __shared__ __align__(16) u16 xT[64][136];
  __shared__ __align__(16) u16 qT[64][136];    // softmaxed queries, [col][ch] bf16
  __shared__ __align__(16) u16 aT[64][136];    // att, [col][ch] bf16
  const int t = threadIdx.x;
  const int w = t >> 6, lane = t & 63;
  const int quad = lane >> 4, lm = lane & 15;
  const int n = blockIdx.x >> 8;
  const int l0base = (blockIdx.x & 255) << 8;

  const int sc = t >> 4;
  const int sl4 = t & 15;

  float4 pf[8];
  #pragma unroll
  for (int i = 0; i < 8; ++i) {
    int c = i * 16 + sc;
    pf[i] = *(const float4*)(x + (((size_t)(n * 128 + c)) << 16) + l0base + sl4 * 4);
  }

  bf16x8 wq[2][4], wr[2][4];
  #pragma unroll
  for (int mt = 0; mt < 2; ++mt)
    #pragma unroll
    for (int ks = 0; ks < 4; ++ks) {
      wq[mt][ks] = *(const bf16x8*)(wqf + ((((w * 2 + mt) * 4 + ks) * 64 + lane) * 8));
      wr[mt][ks] = *(const bf16x8*)(wrf + ((((w * 2 + mt) * 4 + ks) * 64 + lane) * 8));
    }

  // fused kF: build this wave's ctx A-frags from 2-slot Cnum/S (zero-padded k>=16)
  bf16x8 aC[2];
  #pragma unroll
  for (int mt = 0; mt < 2; ++mt) {
    int h = w * 2 + mt;
    short frag[8];
    #pragma unroll
    for (int j = 0; j < 8; ++j) {
      int k = quad * 8 + j;                    // 0..31 over quad
      float v = 0.f;
      if (k < 16) {
        int ci = ((n * 8 + h) * 16 + k) * 16 + lm;
        float c = Cnum2[ci] + Cnum2[4096 + ci];
        float s = S2[n * 128 + h * 16 + k] + S2[256 + n * 128 + h * 16 + k];
        v = c / s;
      }
      frag[j] = (short)f2b(v);
    }
    aC[mt] = *(bf16x8*)frag;
  }

  // block 0: emit context_last + CLS_out (head 7)
  if (blockIdx.x == 0) {
    for (int e = t; e < 512; e += 256) {
      int nn = e >> 8;
      int kc = (e >> 4) & 15;
      int vc = e & 15;
      int ci = ((nn * 8 + 7) * 16 + kc) * 16 + vc;
      float c = Cnum2[ci] + Cnum2[4096 + ci];
      float s = S2[nn * 128 + 112 + kc] + S2[256 + nn * 128 + 112 + kc];
      out[OUT_CTX + e] = c / s;
    }
    if (t < 128) {
      int nn = t >> 6;
      int vc = (t >> 2) & 15;
      int j = t & 3;
      float den = 0.f, num = 0.f;
      #pragma unroll
      for (int kc = 0; kc < 16; ++kc) {
        float e_ = __expf(CLS[(nn * 128 + 112 + kc) * 4 + j]);
        int ci = ((nn * 8 + 7) * 16 + kc) * 16 + vc;
        float c = Cnum2[ci] + Cnum2[4096 + ci];
        float s = S2[nn * 128 + 112 + kc] + S2[256 + nn * 128 + 112 + kc];
        den += e_;
        num += e_ * (c / s);
      }
      out[OUT_CLS + t] = num / den;
    }
  }

  float bqv_[2][4], brv[2][4];
  #pragma unroll
  for (int mt = 0; mt < 2; ++mt)
    #pragma unroll
    for (int j = 0; j < 4; ++j) {
      bqv_[mt][j] = bq[(w * 2 + mt) * 16 + quad * 4 + j];
      brv[mt][j] = br[(w * 2 + mt) * 16 + quad * 4 + j];
    }

  floatx4 z4 = {0.f, 0.f, 0.f, 0.f};

  for (int tile = 0; tile < 4; ++tile) {
    int l0 = l0base + tile * 64;
    #pragma unroll
    for (int i = 0; i < 8; ++i) {
      int cc = i * 16 + sc;
      int col = sl4 * 4;
      xT[col + 0][cc] = f2b(pf[i].x);
      xT[col + 1][cc] = f2b(pf[i].y);
      xT[col + 2][cc] = f2b(pf[i].z);
      xT[col + 3][cc] = f2b(pf[i].w);
    }
    __syncthreads();                          // barrier A

    floatx4 acc[2][4];
    #pragma unroll
    for (int mt = 0; mt < 2; ++mt)
      #pragma unroll
      for (int nt = 0; nt < 4; ++nt) acc[mt][nt] = z4;

    #pragma unroll
    for (int nt = 0; nt < 4; ++nt)
      #pragma unroll
      for (int ks = 0; ks < 4; ++ks) {
        bf16x8 b = *(const bf16x8*)(&xT[nt * 16 + lm][ks * 32 + quad * 8]);
        #pragma unroll
        for (int mt = 0; mt < 2; ++mt)
          acc[mt][nt] = __builtin_amdgcn_mfma_f32_16x16x32_bf16(wq[mt][ks], b, acc[mt][nt], 0, 0, 0);
      }

    // per-column softmax over the 16 channels of each head (wave-local)
    #pragma unroll
    for (int mt = 0; mt < 2; ++mt) {
      int h = w * 2 + mt;
      #pragma unroll
      for (int nt = 0; nt < 4; ++nt) {
        float e[4];
        float ssum = 0.f;
        #pragma unroll
        for (int j = 0; j < 4; ++j) {
          e[j] = __expf(acc[mt][nt][j] + bqv_[mt][j]);
          ssum += e[j];
        }
        ssum += __shfl_xor(ssum, 16);
        ssum += __shfl_xor(ssum, 32);
        float inv = 1.f / ssum;
        #pragma unroll
        for (int j = 0; j < 4; ++j)
          qT[nt * 16 + lm][h * 16 + quad * 4 + j] = f2b(e[j] * inv);
      }
    }
    // same wave wrote these qT rows -> no barrier before reading them back

    // att[h*16+vc, col] = sum_kc ctx[h,kc,vc] * q[h*16+kc, col]  (A zero-padded k>=16)
    #pragma unroll
    for (int mt = 0; mt < 2; ++mt) {
      int h = w * 2 + mt;
      #pragma unroll
      for (int nt = 0; nt < 4; ++nt) {
        bf16x8 bq_ = *(const bf16x8*)(&qT[nt * 16 + lm][h * 16 + (quad & 1) * 8]);
        floatx4 d = __builtin_amdgcn_mfma_f32_16x16x32_bf16(aC[mt], bq_, z4, 0, 0, 0);
        #pragma unroll
        for (int j = 0; j < 4; ++j)
          aT[nt * 16 + lm][h * 16 + quad * 4 + j] = f2b(d[j]);
      }
    }

    // prefetch next tile (overlaps barrier + final GEMM)
    if (tile < 3) {
      int l0n = l0base + (tile + 1) * 64;
      #pragma unroll
      for (int i = 0; i < 8; ++i) {
        int c = i * 16 + sc;
        pf[i] = *(const float4*)(x + (((size_t)(n * 128 + c)) << 16) + l0n + sl4 * 4);
      }
    }
    __syncthreads();                          // barrier B (all heads' att rows ready)

    floatx4 acc2[2][4];
    #pragma unroll
    for (int mt = 0; mt < 2; ++mt)
      #pragma unroll
      for (int nt = 0; nt < 4; ++nt) acc2[mt][nt] = z4;

    #pragma unroll
    for (int nt = 0; nt < 4; ++nt)
      #pragma unroll
      for (int ks = 0; ks < 4; ++ks) {
        bf16x8 b = *(const bf16x8*)(&aT[nt * 16 + lm][ks * 32 + quad * 8]);
        #pragma unroll
        for (int mt = 0; mt < 2; ++mt)
          acc2[mt][nt] = __builtin_amdgcn_mfma_f32_16x16x32_bf16(wr[mt][ks], b, acc2[mt][nt], 0, 0, 0);
      }

    #pragma unroll
    for (int mt = 0; mt < 2; ++mt)
      #pragma unroll
      for (int j = 0; j < 4; ++j) {
        int R = (w * 2 + mt) * 16 + quad * 4 + j;
        #pragma unroll
        for (int nt = 0; nt < 4; ++nt)
          out[(((size_t)(n * 128 + R)) << 16) + l0 + nt * 16 + lm] = acc2[mt][nt][j] + brv[mt][j];
      }
    // next iteration's barrier A protects xT/aT rewrites against this tile's reads
  }
}

extern "C" void kernel_launch(void* const* d_in, const int* in_sizes, int n_in,
                              void* d_out, int out_size, void* d_ws, size_t ws_size,
                              hipStream_t stream) {
  const float* x   = (const float*)d_in[0];
  const float* CLS = (const float*)d_in[1];
  const float* Wk  = (const float*)d_in[2];
  const float* bk  = (const float*)d_in[3];
  const float* Wq  = (const float*)d_in[4];
  const float* bq  = (const float*)d_in[5];
  const float* Wv  = (const float*)d_in[6];
  const float* bv  = (const float*)d_in[7];
  const float* Wr  = (const float*)d_in[8];
  const float* br  = (const float*)d_in[9];
  float* out = (float*)d_out;
  char* ws = (char*)d_ws;
  float* S2    = (float*)(ws + 0);        // 2 slots x 2n x 128 f32 = 2048 B
  float* Cnum2 = (float*)(ws + 2048);     // 2 slots x 4096 f32 = 32768 B
  u16* wkv     = (u16*)(ws + 34816);      // 16*4*64*8 bf16 = 65536 B
  u16* wqf     = (u16*)(ws + 100352);     // 8*4*64*8 bf16 = 32768 B
  u16* wrf     = (u16*)(ws + 133120);     // 8*4*64*8 bf16 = 32768 B

  kP<<<33, 256, 0, stream>>>(Wk, Wq, Wv, Wr, CLS, S2, Cnum2, wkv, wqf, wrf);
  kA<<<512, 256, 0, stream>>>(x, bk, bv, S2, Cnum2, wkv);
  kB<<<512, 256, 0, stream>>>(x, bq, br, wqf, wrf, S2, Cnum2, CLS, out);
}